// Round 1
// baseline (131.760 us; speedup 1.0000x reference)
//
#include <hip/hip_runtime.h>

// Problem constants
#define NB    32      // batch
#define DM    64      // embedding dim
#define HWN   1024    // H*W
#define NROWS 32768   // NB*HWN
#define ECNT  1024    // num embeddings
#define QOUT  2097152 // quantized elements (NB*DM*HWN)

// ---------------- kernel 0: half squared norms of codes ----------------
__global__ void vq_norms(const float* __restrict__ emb, float* __restrict__ nrm) {
    int c = blockIdx.x * blockDim.x + threadIdx.x;  // 0..1023
    if (c >= ECNT) return;
    const float4* e4 = reinterpret_cast<const float4*>(emb + c * DM);
    float s = 0.f;
#pragma unroll
    for (int i = 0; i < 16; ++i) {
        float4 v = e4[i];
        s += v.x * v.x + v.y * v.y + v.z * v.z + v.w * v.w;
    }
    nrm[c] = 0.5f * s;
}

// ---------------- kernel 1: main VQ ----------------
// 512 blocks x 256 threads. Block handles 64 consecutive rows (same b).
// thread t: row r = t&63, code-group g = t>>6 (256 codes each).
__global__ __launch_bounds__(256, 2) void vq_main(
    const float* __restrict__ z, const float* __restrict__ emb,
    const float* __restrict__ nrm, float* __restrict__ out,
    float* __restrict__ partial)
{
    __shared__ float zlds[64][65];        // +1 pad: conflict-free row reads
    __shared__ float elds[4][32][64];     // 4 groups x 32 codes x 64 dims
    __shared__ float nlds[4][32];
    __shared__ float mb0[256];
    __shared__ float mb1[256];
    __shared__ int   mi0[256];
    __shared__ int   mi1[256];

    const int t   = threadIdx.x;
    const int bi  = blockIdx.x;
    const int n0  = bi * 64;
    const int b   = n0 >> 10;
    const int hw0 = n0 & (HWN - 1);

    // stage z tile: zlds[j][d] = z[b, d, hw0+j]  (coalesced across j)
#pragma unroll
    for (int k = 0; k < 16; ++k) {
        int l = k * 256 + t;
        int d = l >> 6, j = l & 63;
        zlds[j][d] = z[((b * DM + d) << 10) + hw0 + j];
    }
    __syncthreads();

    const int r = t & 63;
    const int g = t >> 6;

    float zv[64];
#pragma unroll
    for (int d = 0; d < 64; ++d) zv[d] = zlds[r][d];

    float b0 = 1e30f, b1 = 1e30f;
    int   i0 = 0,     i1 = 0;

    for (int it = 0; it < 8; ++it) {
        __syncthreads();
        // stage 128 codes (32 per group) as float4, fully coalesced
#pragma unroll
        for (int k = 0; k < 8; ++k) {
            int l4 = k * 256 + t;
            int c  = l4 >> 4;       // 0..127
            int d4 = l4 & 15;
            int gg = c >> 5, cc = c & 31;
            int code = gg * 256 + it * 32 + cc;
            reinterpret_cast<float4*>(&elds[gg][cc][0])[d4] =
                reinterpret_cast<const float4*>(emb)[code * 16 + d4];
        }
        if (t < 128) {
            int gg = t >> 5, cc = t & 31;
            nlds[gg][cc] = nrm[gg * 256 + it * 32 + cc];
        }
        __syncthreads();

        for (int cc = 0; cc < 32; ++cc) {
            const float4* e4 = reinterpret_cast<const float4*>(&elds[g][cc][0]);
            float a0 = 0.f, a1 = 0.f, a2 = 0.f, a3 = 0.f;
#pragma unroll
            for (int q4 = 0; q4 < 16; ++q4) {
                float4 ev = e4[q4];       // wave-uniform address -> LDS broadcast
                int d = q4 * 4;
                a0 = fmaf(zv[d + 0], ev.x, a0);
                a1 = fmaf(zv[d + 1], ev.y, a1);
                a2 = fmaf(zv[d + 2], ev.z, a2);
                a3 = fmaf(zv[d + 3], ev.w, a3);
            }
            float dist = nlds[g][cc] - ((a0 + a1) + (a2 + a3));  // 0.5||e||^2 - z.e
            int code = (g << 8) + (it << 5) + cc;
            if (dist < b0)      { b1 = b0; i1 = i0; b0 = dist; i0 = code; }
            else if (dist < b1) { b1 = dist; i1 = code; }
        }
    }

    __syncthreads();
    mb0[t] = b0; mb1[t] = b1; mi0[t] = i0; mi1[t] = i1;
    __syncthreads();

    if (t < 64) {
        float B0 = mb0[t], B1 = mb1[t];
        int   I0 = mi0[t], I1 = mi1[t];
#pragma unroll
        for (int gg = 1; gg < 4; ++gg) {
            int u = gg * 64 + t;
            float cb = mb0[u], cs = mb1[u];
            int   ci = mi0[u], cj = mi1[u];
            if (cb < B0) {
                if (B0 <= cs) { B1 = B0; I1 = I0; }
                else          { B1 = cs; I1 = cj; }
                B0 = cb; I0 = ci;
            } else if (cb < B1) { B1 = cb; I1 = ci; }
        }
        // fp64 refinement of near-ties (protects argmin vs reference rounding)
        if (B1 - B0 < 5e-3f) {
            const float* ea = emb + I0 * DM;
            const float* eb = emb + I1 * DM;
            double sa = 0.0, sb = 0.0, na = 0.0, nb = 0.0;
            for (int d = 0; d < 64; ++d) {
                double zd = (double)zlds[t][d];
                double va = (double)ea[d], vb = (double)eb[d];
                sa += zd * va; na += va * va;
                sb += zd * vb; nb += vb * vb;
            }
            double da = 0.5 * na - sa, db = 0.5 * nb - sb;
            if (db < da || (db == da && I1 < I0)) I0 = I1;
        }
        // gather chosen code, write quantized (B,D,H,W layout), accumulate error
        const float* eq = emb + I0 * DM;
        float err = 0.f;
#pragma unroll
        for (int d = 0; d < 64; ++d) {
            float qv = eq[d];
            float df = zlds[t][d] - qv;
            err = fmaf(df, df, err);
            out[((b * DM + d) << 10) + hw0 + t] = qv;   // coalesced across t
        }
        out[QOUT + 1 + n0 + t] = (float)I0;             // index as float
        mb0[t] = err;
    }
    __syncthreads();
    if (t == 0) {
        float s = 0.f;
        for (int d = 0; d < 64; ++d) s += mb0[d];
        partial[bi] = s;
    }
}

// ---------------- kernel 2: deterministic loss reduction ----------------
__global__ void vq_reduce(const float* __restrict__ partial, float* __restrict__ out) {
    __shared__ float s[256];
    int t = threadIdx.x;
    s[t] = partial[t] + partial[t + 256];
    __syncthreads();
    for (int w = 128; w > 0; w >>= 1) {
        if (t < w) s[t] += s[t + w];
        __syncthreads();
    }
    if (t == 0) out[QOUT] = 1.25f * s[0] * (1.0f / (float)QOUT);
}

extern "C" void kernel_launch(void* const* d_in, const int* in_sizes, int n_in,
                              void* d_out, int out_size, void* d_ws, size_t ws_size,
                              hipStream_t stream) {
    const float* z   = (const float*)d_in[0];
    const float* emb = (const float*)d_in[1];
    float* out = (float*)d_out;
    float* nrm = (float*)d_ws;          // 1024 floats
    float* partial = nrm + ECNT;        // 512 floats

    vq_norms <<<4,   256, 0, stream>>>(emb, nrm);
    vq_main  <<<512, 256, 0, stream>>>(z, emb, nrm, out, partial);
    vq_reduce<<<1,   256, 0, stream>>>(partial, out);
}

// Round 2
// 38.507 us; speedup vs baseline: 3.4217x; 3.4217x over previous
//
#include <hip/hip_runtime.h>

typedef __attribute__((ext_vector_type(8))) short short8;
typedef __attribute__((ext_vector_type(4))) float f32x4;
typedef unsigned int uint32;

#define DMQ 64
#define QOUT 2097152

__device__ __forceinline__ unsigned short f2bf(float f){
  uint32 u = __float_as_uint(f);
  return (unsigned short)((u + 0x7FFFu + ((u >> 16) & 1u)) >> 16);
}
__device__ __forceinline__ float bf2f(unsigned short h){
  return __uint_as_float(((uint32)h) << 16);
}
__device__ __forceinline__ uint32 med3u(uint32 a, uint32 b, uint32 c){
  uint32 d;
  asm("v_med3_u32 %0, %1, %2, %3" : "=v"(d) : "v"(a), "v"(b), "v"(c));
  return d;
}
__device__ __forceinline__ void glds16(const unsigned char* g, unsigned char* l){
  __builtin_amdgcn_global_load_lds(
      (const __attribute__((address_space(1))) unsigned int*)g,
      (__attribute__((address_space(3))) unsigned int*)l, 16, 0, 0);
}

// ---------- kernel 0: split E into hi/lo bf16 in swizzled chunk layout + norms ----------
// ebg layout: chunk c (256 codes) at c*65536; [0,32768)=hi, [32768,65536)=lo.
// Within: code cc row = cc*128 bytes; 8B sub-block 'sub' stored at ((sub ^ ((cc&7)<<1))<<3).
__global__ void vq_prep(const float* __restrict__ emb,
                        unsigned char* __restrict__ ebg,
                        float* __restrict__ nrm64){
  int C = blockIdx.x * 256 + threadIdx.x;   // 0..1023
  const float4* e4 = reinterpret_cast<const float4*>(emb + C * DMQ);
  int chunk = C >> 8, cc = C & 255;
  unsigned char* eb = ebg + chunk * 65536;
  int x = (cc & 7) << 1;
  float s = 0.f;
#pragma unroll
  for (int sub = 0; sub < 16; ++sub){
    float4 v = e4[sub];
    s += v.x*v.x + v.y*v.y + v.z*v.z + v.w*v.w;
    ushort4 h, l;
    h.x = f2bf(v.x); l.x = f2bf(v.x - bf2f(h.x));
    h.y = f2bf(v.y); l.y = f2bf(v.y - bf2f(h.y));
    h.z = f2bf(v.z); l.z = f2bf(v.z - bf2f(h.z));
    h.w = f2bf(v.w); l.w = f2bf(v.w - bf2f(h.w));
    int off = cc * 128 + ((sub ^ x) << 3);
    *reinterpret_cast<ushort4*>(eb + off) = h;
    *reinterpret_cast<ushort4*>(eb + 32768 + off) = l;
  }
  nrm64[C] = 0.5f * s + 128.0f;   // +128 keeps keys positive & exponent small
}

// ---------- kernel 1: MFMA distance + fused top-3 argmin ----------
// 512 blocks x 256 thr (4 waves). Block: 64 rows. Wave (wm,wn): rows wm*32..+32,
// codes wn*128 within each staged 256-code chunk.
__global__ __launch_bounds__(256, 2) void vq_main(
    const float* __restrict__ z, const float* __restrict__ emb,
    const unsigned char* __restrict__ ebg, const float* __restrict__ nrm64,
    float* __restrict__ out, float* __restrict__ partial)
{
  __shared__ __align__(16) unsigned char LB[65536];
  __shared__ float nrmlds[1024];
  __shared__ uint32 mg[64][2][3];
  __shared__ int kidx[64];
  __shared__ float perr[256];

  const int t = threadIdx.x;
  const int bi = blockIdx.x;
  const int n0 = bi * 64;
  const int b = n0 >> 10;
  const int hw0 = n0 & 1023;
  const int w = t >> 6, lane = t & 63;
  const int wm = w >> 1, wn = w & 1;
  const int l15 = lane & 15, g = lane >> 4;

  for (int i = t; i < 1024; i += 256) nrmlds[i] = nrm64[i];

  // stage z tile as zf[64][68] (overlaid in LB)
  float* zf = reinterpret_cast<float*>(LB);
#pragma unroll
  for (int k = 0; k < 16; ++k){
    int li = k * 256 + t;
    int d = li >> 6, j = li & 63;
    zf[j * 68 + d] = z[((b * DMQ + d) << 10) + hw0 + j];
  }
  __syncthreads();

  // A-fragments of (-z), hi/lo bf16. A layout: row=lane&15, k=(lane>>4)*8+j.
  short8 ah[2][2], al[2][2];
#pragma unroll
  for (int mf = 0; mf < 2; ++mf)
#pragma unroll
    for (int kf = 0; kf < 2; ++kf){
      int row = wm * 32 + mf * 16 + l15;
      int base = row * 68 + kf * 32 + g * 8;
      float4 q0 = *reinterpret_cast<float4*>(&zf[base]);
      float4 q1 = *reinterpret_cast<float4*>(&zf[base + 4]);
      float vv[8] = {q0.x,q0.y,q0.z,q0.w,q1.x,q1.y,q1.z,q1.w};
#pragma unroll
      for (int j = 0; j < 8; ++j){
        float v = -vv[j];
        unsigned short hs = f2bf(v);
        unsigned short ls = f2bf(v - bf2f(hs));
        ah[mf][kf][j] = (short)hs;
        al[mf][kf][j] = (short)ls;
      }
    }
  __syncthreads();   // done reading zf; LB free for chunks

  uint32 u0[8], u1[8], u2[8];
#pragma unroll
  for (int s = 0; s < 8; ++s){ u0[s] = 0xFFFFFFFFu; u1[s] = 0xFFFFFFFFu; u2[s] = 0xFFFFFFFFu; }

  const int cc0 = wn * 128 + l15;
  const int xsw = (l15 & 7) << 1;
  const int v0s = ((g * 2) ^ xsw) << 3;       // kf=0 swizzled byte offset
  const int v1s = ((8 + g * 2) ^ xsw) << 3;   // kf=1

  for (int c = 0; c < 4; ++c){
    const unsigned char* src = ebg + c * 65536;
#pragma unroll
    for (int r = 0; r < 16; ++r){
      int off = (r * 4 + w) * 1024;
      glds16(src + off + lane * 16, LB + off);   // HW adds lane*16 on LDS side
    }
    __syncthreads();   // drains global_load_lds

#pragma unroll
    for (int nf = 0; nf < 8; ++nf){
      int cc = cc0 + nf * 16;
      const unsigned char* rb = LB + cc * 128;
      short8 bh0 = *reinterpret_cast<const short8*>(rb + v0s);
      short8 bh1 = *reinterpret_cast<const short8*>(rb + v1s);
      short8 bl0 = *reinterpret_cast<const short8*>(rb + 32768 + v0s);
      short8 bl1 = *reinterpret_cast<const short8*>(rb + 32768 + v1s);
      float nv = nrmlds[(c << 8) + cc];
      f32x4 a0 = {nv, nv, nv, nv};
      f32x4 a1 = {nv, nv, nv, nv};
      a0 = __builtin_amdgcn_mfma_f32_16x16x32_bf16(ah[0][0], bh0, a0, 0,0,0);
      a0 = __builtin_amdgcn_mfma_f32_16x16x32_bf16(ah[0][1], bh1, a0, 0,0,0);
      a0 = __builtin_amdgcn_mfma_f32_16x16x32_bf16(al[0][0], bh0, a0, 0,0,0);
      a0 = __builtin_amdgcn_mfma_f32_16x16x32_bf16(al[0][1], bh1, a0, 0,0,0);
      a0 = __builtin_amdgcn_mfma_f32_16x16x32_bf16(ah[0][0], bl0, a0, 0,0,0);
      a0 = __builtin_amdgcn_mfma_f32_16x16x32_bf16(ah[0][1], bl1, a0, 0,0,0);
      a1 = __builtin_amdgcn_mfma_f32_16x16x32_bf16(ah[1][0], bh0, a1, 0,0,0);
      a1 = __builtin_amdgcn_mfma_f32_16x16x32_bf16(ah[1][1], bh1, a1, 0,0,0);
      a1 = __builtin_amdgcn_mfma_f32_16x16x32_bf16(al[1][0], bh0, a1, 0,0,0);
      a1 = __builtin_amdgcn_mfma_f32_16x16x32_bf16(al[1][1], bh1, a1, 0,0,0);
      a1 = __builtin_amdgcn_mfma_f32_16x16x32_bf16(ah[1][0], bl0, a1, 0,0,0);
      a1 = __builtin_amdgcn_mfma_f32_16x16x32_bf16(ah[1][1], bl1, a1, 0,0,0);
      uint32 kb = (uint32)((c << 8) | cc0 | (nf << 4));
#pragma unroll
      for (int r = 0; r < 4; ++r){
        uint32 k0v = (__float_as_uint(a0[r]) & 0xFFFFFC00u) | kb;
        u2[r] = med3u(k0v, u1[r], u2[r]);
        u1[r] = med3u(k0v, u0[r], u1[r]);
        u0[r] = u0[r] < k0v ? u0[r] : k0v;
        uint32 k1v = (__float_as_uint(a1[r]) & 0xFFFFFC00u) | kb;
        u2[4+r] = med3u(k1v, u1[4+r], u2[4+r]);
        u1[4+r] = med3u(k1v, u0[4+r], u1[4+r]);
        u0[4+r] = u0[4+r] < k1v ? u0[4+r] : k1v;
      }
    }
    __syncthreads();   // all waves done with LB before restage
  }

  // butterfly top-3 merge across the 16 col-lanes (same rows share lane>>4)
#pragma unroll
  for (int dm = 1; dm < 16; dm <<= 1){
#pragma unroll
    for (int s = 0; s < 8; ++s){
      uint32 x0 = (uint32)__shfl_xor((int)u0[s], dm);
      uint32 x1 = (uint32)__shfl_xor((int)u1[s], dm);
      uint32 x2 = (uint32)__shfl_xor((int)u2[s], dm);
      u2[s] = med3u(x0, u1[s], u2[s]); u1[s] = med3u(x0, u0[s], u1[s]); u0[s] = u0[s] < x0 ? u0[s] : x0;
      u2[s] = med3u(x1, u1[s], u2[s]); u1[s] = med3u(x1, u0[s], u1[s]); u0[s] = u0[s] < x1 ? u0[s] : x1;
      u2[s] = med3u(x2, u1[s], u2[s]); u1[s] = med3u(x2, u0[s], u1[s]); u0[s] = u0[s] < x2 ? u0[s] : x2;
    }
  }
  if (l15 == 0){
#pragma unroll
    for (int mf = 0; mf < 2; ++mf)
#pragma unroll
      for (int r = 0; r < 4; ++r){
        int lr = wm * 32 + mf * 16 + g * 4 + r;
        int s = mf * 4 + r;
        mg[lr][wn][0] = u0[s]; mg[lr][wn][1] = u1[s]; mg[lr][wn][2] = u2[s];
      }
  }
  __syncthreads();

  if (t < 64){
    uint32 a0k = mg[t][0][0], a1k = mg[t][0][1], a2k = mg[t][0][2];
#pragma unroll
    for (int j = 0; j < 3; ++j){
      uint32 x = mg[t][1][j];
      a2k = med3u(x, a1k, a2k); a1k = med3u(x, a0k, a1k); a0k = a0k < x ? a0k : x;
    }
    int k0 = (int)(a0k & 1023u);
    float d0 = __uint_as_float(a0k & 0xFFFFFC00u);
    float d1 = __uint_as_float(a1k & 0xFFFFFC00u);
    if (d1 - d0 < 0.125f){   // fp64 re-check of near-ties
      int k1 = (int)(a1k & 1023u);
      int k2 = (int)(a2k & 1023u);
      float d2v = __uint_as_float(a2k & 0xFFFFFC00u);
      bool c2 = (d2v - d0 < 0.125f);
      const float* zb = z + (b << 16) + hw0 + t;
      const float* e0 = emb + k0 * DMQ;
      const float* e1 = emb + k1 * DMQ;
      const float* e2 = emb + k2 * DMQ;
      double s0 = 0.0, s1 = 0.0, s2 = 0.0;
      for (int d = 0; d < DMQ; ++d){
        double zd = (double)zb[d << 10];
        double t0 = zd - (double)e0[d]; s0 += t0 * t0;
        double t1 = zd - (double)e1[d]; s1 += t1 * t1;
        double t2 = zd - (double)e2[d]; s2 += t2 * t2;
      }
      int bk = k0; double bs = s0;
      if (s1 < bs || (s1 == bs && k1 < bk)) { bs = s1; bk = k1; }
      if (c2 && (s2 < bs || (s2 == bs && k2 < bk))) { bs = s2; bk = k2; }
      k0 = bk;
    }
    kidx[t] = k0;
    out[QOUT + 1 + n0 + t] = (float)k0;
  }
  __syncthreads();

  // quantized write + squared error, all 256 threads (coalesced across t&63)
  {
    int row = t & 63, dp = t >> 6;
    int k = kidx[row];
    const float* e = emb + k * DMQ;
    const float* zb = z + (b << 16) + hw0 + row;
    float* ob = out + (b << 16) + hw0 + row;
    float err = 0.f;
#pragma unroll
    for (int dd = 0; dd < 16; ++dd){
      int d = dp * 16 + dd;
      float zv = zb[d << 10];
      float qv = e[d];
      ob[d << 10] = qv;
      float df = zv - qv;
      err = fmaf(df, df, err);
    }
    perr[t] = err;
  }
  __syncthreads();
  for (int ww = 128; ww > 0; ww >>= 1){
    if (t < ww) perr[t] += perr[t + ww];
    __syncthreads();
  }
  if (t == 0) partial[bi] = perr[0];
}

// ---------- kernel 2: deterministic loss reduction ----------
__global__ void vq_reduce(const float* __restrict__ partial, float* __restrict__ out) {
  __shared__ float s[256];
  int t = threadIdx.x;
  s[t] = partial[t] + partial[t + 256];
  __syncthreads();
  for (int w = 128; w > 0; w >>= 1) {
    if (t < w) s[t] += s[t + w];
    __syncthreads();
  }
  if (t == 0) out[QOUT] = 1.25f * s[0] * (1.0f / (float)QOUT);
}

extern "C" void kernel_launch(void* const* d_in, const int* in_sizes, int n_in,
                              void* d_out, int out_size, void* d_ws, size_t ws_size,
                              hipStream_t stream) {
  const float* z   = (const float*)d_in[0];
  const float* emb = (const float*)d_in[1];
  float* out = (float*)d_out;
  unsigned char* ebg = (unsigned char*)d_ws;       // 262144 B
  float* nrm64  = (float*)(ebg + 262144);          // 1024 floats
  float* partial = nrm64 + 1024;                   // 512 floats

  vq_prep  <<<4,   256, 0, stream>>>(emb, ebg, nrm64);
  vq_main  <<<512, 256, 0, stream>>>(z, emb, ebg, nrm64, out, partial);
  vq_reduce<<<1,   256, 0, stream>>>(partial, out);
}